// Round 7
// baseline (41.746 us; speedup 1.0000x reference)
//
#include <hip/hip_runtime.h>
#include <cstdint>
#include <cstddef>

typedef __attribute__((ext_vector_type(8))) short short8;
typedef __attribute__((ext_vector_type(4))) unsigned short ushort4_t;
typedef __attribute__((ext_vector_type(16))) float f32x16;

#define NF 40
#define NK 780           // 40*39/2 pairs
#define BT 32            // batch rows per block
#define THREADS 1024     // 16 waves, grid 256 = 1 block/CU

__device__ __forceinline__ unsigned short f2bf(float f) {
    unsigned int u = __float_as_uint(f);
    u = (u + 0x7fffu + ((u >> 16) & 1u)) >> 16;
    return (unsigned short)u;
}
__device__ __forceinline__ float bf2f(unsigned short x) {
    return __uint_as_float(((unsigned int)x) << 16);
}

// wfrag[k][half][l][t] = bf16( W[k][ e = l&31 ][ 16*half + 8*(l>>5) + t ] )
// = A-fragment (rows e, K-dim f) for mfma_f32_32x32x16_bf16; half = f-half.
__global__ __launch_bounds__(128) void wprep_kernel(const float* __restrict__ W,
                                                    unsigned short* __restrict__ wfrag) {
    const int k = blockIdx.x, t = threadIdx.x;
    const int half = t >> 6, l = t & 63;
    const int e = l & 31;
    const int f0 = 16 * half + 8 * (l >> 5);
    const float* src = W + (size_t)k * 1024 + e * 32 + f0;
    const float4 x0 = *(const float4*)src;
    const float4 x1 = *(const float4*)(src + 4);
    short8 v;
    v[0] = (short)f2bf(x0.x); v[1] = (short)f2bf(x0.y);
    v[2] = (short)f2bf(x0.z); v[3] = (short)f2bf(x0.w);
    v[4] = (short)f2bf(x1.x); v[5] = (short)f2bf(x1.y);
    v[6] = (short)f2bf(x1.z); v[7] = (short)f2bf(x1.w);
    *(short8*)(wfrag + (size_t)k * 1024 + half * 512 + l * 8) = v;
}

// --- forced-pipeline primitives -------------------------------------------------
// 4 x 16B loads for a 2-k W-fragment group; asm volatile => compiler cannot sink.
__device__ __forceinline__ void ld_w4(short8& r0, short8& r1, short8& r2, short8& r3,
                                      const char* addr) {
    asm volatile("global_load_dwordx4 %0, %4, off\n\t"
                 "global_load_dwordx4 %1, %4, off offset:1024\n\t"
                 "global_load_dwordx4 %2, %4, off offset:2048\n\t"
                 "global_load_dwordx4 %3, %4, off offset:3072"
                 : "=&v"(r0), "=&v"(r1), "=&v"(r2), "=&v"(r3)
                 : "v"(addr));
}
// Wait until only the newest 4 vmem ops (the just-issued prefetch) are outstanding,
// then hard-fence the scheduler so no MFMA consumes W regs before data lands (rule #18).
#define WAITP() do { asm volatile("s_waitcnt vmcnt(4)" ::: "memory"); \
                     __builtin_amdgcn_sched_barrier(0); } while (0)
#define WAIT0() do { asm volatile("s_waitcnt vmcnt(0)" ::: "memory"); \
                     __builtin_amdgcn_sched_barrier(0); } while (0)

#define LOADW2(R0, R1, R2, R3, KB)                                                      \
    {                                                                                   \
        const int kbc = (KB) > 778 ? 778 : (KB);                                        \
        ld_w4(R0, R1, R2, R3, wbase + ((size_t)kbc << 11));                             \
    }

// embT granule (field, g): g = (b + 32*fq) ^ (field&7), holds bf16 of
// emb[b0+b][field][8*fq .. 8*fq+7]. XOR spreads bank-quads on both sides.

// vi f32 cache for lane's b-col: vf[4q+s] = vi[b32][8q + 4*h32 + s]  (C rows)
#define RELOAD_VI()                                                                     \
    {                                                                                   \
        const int i7 = ii & 7;                                                          \
        const char* ibase = embT + (ii << 11) + eoff;                                   \
        const ushort4_t r0 = *(const ushort4_t*)(ibase + (((b32     ) ^ i7) << 4));     \
        const ushort4_t r1 = *(const ushort4_t*)(ibase + (((b32 + 32) ^ i7) << 4));     \
        const ushort4_t r2 = *(const ushort4_t*)(ibase + (((b32 + 64) ^ i7) << 4));     \
        const ushort4_t r3 = *(const ushort4_t*)(ibase + (((b32 + 96) ^ i7) << 4));     \
        vf0  = bf2f(r0[0]); vf1  = bf2f(r0[1]); vf2  = bf2f(r0[2]); vf3  = bf2f(r0[3]); \
        vf4  = bf2f(r1[0]); vf5  = bf2f(r1[1]); vf6  = bf2f(r1[2]); vf7  = bf2f(r1[3]); \
        vf8  = bf2f(r2[0]); vf9  = bf2f(r2[1]); vf10 = bf2f(r2[2]); vf11 = bf2f(r2[3]); \
        vf12 = bf2f(r3[0]); vf13 = bf2f(r3[1]); vf14 = bf2f(r3[2]); vf15 = bf2f(r3[3]); \
    }

// one k: t[e,b] = W[k]·vj (2 chained 32x32x16 over f-halves), dot with cached vi, reduce
#define KSTEP(A0, A1, OREG)                                                             \
    {                                                                                   \
        const int j7 = jj & 7;                                                          \
        const char* jbase = embT + (jj << 11);                                          \
        const short8 vj0 = *(const short8*)(jbase + (((b32 + fq0) ^ j7) << 4));         \
        const short8 vj1 = *(const short8*)(jbase + (((b32 + fq1) ^ j7) << 4));         \
        f32x16 t = {};                                                                  \
        t = __builtin_amdgcn_mfma_f32_32x32x16_bf16(A0, vj0, t, 0, 0, 0);               \
        t = __builtin_amdgcn_mfma_f32_32x32x16_bf16(A1, vj1, t, 0, 0, 0);               \
        float p = t[0]*vf0  + t[1]*vf1  + t[2]*vf2   + t[3]*vf3                         \
                + t[4]*vf4  + t[5]*vf5  + t[6]*vf6   + t[7]*vf7                         \
                + t[8]*vf8  + t[9]*vf9  + t[10]*vf10 + t[11]*vf11                       \
                + t[12]*vf12+ t[13]*vf13+ t[14]*vf14 + t[15]*vf15;                      \
        p += __shfl_xor(p, 32);                                                         \
        OREG = p;                                                                       \
        ++jj;                                                                           \
        if (jj == NF) { ++ii; jj = ii + 1; RELOAD_VI(); }                               \
    }

// prefetch next group into N*, wait for current group C*, compute its 2 k's
#define STEP2(KNEXT, C0, C1, C2, C3, N0, N1, N2, N3, OA, OB)                            \
    LOADW2(N0, N1, N2, N3, KNEXT);                                                      \
    WAITP();                                                                            \
    KSTEP(C0, C1, OA);                                                                  \
    KSTEP(C2, C3, OB);

__global__ __launch_bounds__(THREADS) void bil_kernel(const float* __restrict__ emb,
                                                      const unsigned short* __restrict__ wfrag,
                                                      float* __restrict__ out) {
    __shared__ __align__(16) char embT[NF * 2048];   // 81920 B

    const int tid = threadIdx.x;
    const int b0 = blockIdx.x * BT;

    // --- Stage 32-row tile: coalesced 32B global reads, conflict-free swizzled LDS writes ---
    for (int u = tid; u < BT * 160; u += THREADS) {  // exactly 5 iterations
        const int bb = u / 160;
        const int t = u - 160 * bb;
        const int field = t >> 2;
        const int fq = t & 3;
        const float* src = emb + (size_t)(b0 + bb) * (NF * 32) + field * 32 + 8 * fq;
        const float4 x0 = *(const float4*)src;
        const float4 x1 = *(const float4*)(src + 4);
        short8 v;
        v[0] = (short)f2bf(x0.x); v[1] = (short)f2bf(x0.y);
        v[2] = (short)f2bf(x0.z); v[3] = (short)f2bf(x0.w);
        v[4] = (short)f2bf(x1.x); v[5] = (short)f2bf(x1.y);
        v[6] = (short)f2bf(x1.z); v[7] = (short)f2bf(x1.w);
        const int g = (bb + 32 * fq) ^ (field & 7);
        *(short8*)(embT + field * 2048 + g * 16) = v;
    }
    __syncthreads();

    const int ww = tid >> 6;            // wave 0..15
    const int l = tid & 63;
    const int b32 = l & 31;             // lane's batch row (C col)
    const int h32 = l >> 5;
    const int fq0 = 32 * h32;           // vj granule offset, f-half 0
    const int fq1 = 64 + 32 * h32;      // f-half 1
    const int eoff = 8 * h32;           // byte offset within vi granule

    // k-range per wave, multiple of 4 (48 or 52 k each)
    const int ks = 4 * ((195 * ww) >> 4);
    const int ke = 4 * ((195 * (ww + 1)) >> 4);

    // initial (ii, jj) for k = ks  (i-major triu order)
    int ii = 0, jj;
    {
        int kk = ks, len = 39;
        while (kk >= len) { kk -= len; ++ii; --len; }
        jj = ii + 1 + kk;
    }

    float vf0, vf1, vf2, vf3, vf4, vf5, vf6, vf7;
    float vf8, vf9, vf10, vf11, vf12, vf13, vf14, vf15;
    RELOAD_VI();

    const char* wbase = (const char*)wfrag + l * 16;

    short8 a0, a1, a2, a3;      // bank A: one 2-k group's fragments
    short8 bb0, bb1, bb2, bb3;  // bank B
    LOADW2(a0, a1, a2, a3, ks);

    int kcur = ks;
    while (kcur + 16 <= ke) {            // 16-k superblock: 8 pipelined groups
        float o0, o1, o2, o3, o4, o5, o6, o7;
        float o8, o9, o10, o11, o12, o13, o14, o15;
        STEP2(kcur + 2,  a0, a1, a2, a3, bb0, bb1, bb2, bb3, o0,  o1)
        STEP2(kcur + 4,  bb0, bb1, bb2, bb3, a0, a1, a2, a3, o2,  o3)
        STEP2(kcur + 6,  a0, a1, a2, a3, bb0, bb1, bb2, bb3, o4,  o5)
        STEP2(kcur + 8,  bb0, bb1, bb2, bb3, a0, a1, a2, a3, o6,  o7)
        STEP2(kcur + 10, a0, a1, a2, a3, bb0, bb1, bb2, bb3, o8,  o9)
        STEP2(kcur + 12, bb0, bb1, bb2, bb3, a0, a1, a2, a3, o10, o11)
        STEP2(kcur + 14, a0, a1, a2, a3, bb0, bb1, bb2, bb3, o12, o13)
        STEP2(kcur + 16, bb0, bb1, bb2, bb3, a0, a1, a2, a3, o14, o15)
        if (l < 32) {                    // 64 contiguous bytes per lane: full sectors
            float* orow = out + (size_t)(b0 + l) * NK + kcur;
            float4 s;
            s.x = o0;  s.y = o1;  s.z = o2;  s.w = o3;  *(float4*)(orow)      = s;
            s.x = o4;  s.y = o5;  s.z = o6;  s.w = o7;  *(float4*)(orow + 4)  = s;
            s.x = o8;  s.y = o9;  s.z = o10; s.w = o11; *(float4*)(orow + 8)  = s;
            s.x = o12; s.y = o13; s.z = o14; s.w = o15; *(float4*)(orow + 12) = s;
        }
        kcur += 16;
    }
    if (kcur < ke) {                     // 4-k tail; bank A holds kcur's group
        float o0, o1, o2, o3;
        LOADW2(bb0, bb1, bb2, bb3, kcur + 2);
        WAITP();
        KSTEP(a0, a1, o0);
        KSTEP(a2, a3, o1);
        WAIT0();
        KSTEP(bb0, bb1, o2);
        KSTEP(bb2, bb3, o3);
        if (l < 32) {
            float4 s; s.x = o0; s.y = o1; s.z = o2; s.w = o3;
            *(float4*)(out + (size_t)(b0 + l) * NK + kcur) = s;
        }
    }
}

extern "C" void kernel_launch(void* const* d_in, const int* in_sizes, int n_in,
                              void* d_out, int out_size, void* d_ws, size_t ws_size,
                              hipStream_t stream) {
    const float* emb = (const float*)d_in[0];
    const float* W   = (const float*)d_in[1];
    float* out = (float*)d_out;
    unsigned short* wfrag = (unsigned short*)d_ws;   // 780*1024*2 B = 1.6 MB scratch

    wprep_kernel<<<dim3(NK), dim3(128), 0, stream>>>(W, wfrag);
    bil_kernel<<<dim3(8192 / BT), dim3(THREADS), 0, stream>>>(emb, wfrag, out);
}